// Round 1
// baseline (976.048 us; speedup 1.0000x reference)
//
#include <hip/hip_runtime.h>
#include <stdint.h>

#define MROWS 1536
#define NCOLS 16384
#define NTT 100      // thresholds / roc columns
#define NTHR 99      // thresholds actually used
#define NTHREADS 1024
#define NWAVES 16

// order-preserving float->uint key transform
__device__ __forceinline__ uint32_t f2k(float f) {
  uint32_t y = __float_as_uint(f);
  return (y & 0x80000000u) ? ~y : (y | 0x80000000u);
}
__device__ __forceinline__ float k2f(uint32_t k) {
  uint32_t y = (k & 0x80000000u) ? (k & 0x7fffffffu) : ~k;
  return __uint_as_float(y);
}

// One stable LSD radix pass (8-bit digit) of 16384 keys, LDS src -> LDS dst.
// Wave w owns contiguous segment [w*1024, (w+1)*1024), batches of 64 in order,
// lanes in order => globally stable.
__device__ __forceinline__ void radix_pass(const uint32_t* __restrict__ src,
                                           uint32_t* __restrict__ dst,
                                           uint32_t* sHist, uint32_t* sWsum,
                                           int shift, int tid, int lane, int w) {
  for (int i = tid; i < NWAVES * 256; i += NTHREADS) sHist[i] = 0u;
  __syncthreads();

  uint32_t kreg[16];
  const int segbase = w << 10;
  #pragma unroll
  for (int b = 0; b < 16; ++b) {
    uint32_t k = src[segbase + (b << 6) + lane];
    kreg[b] = k;
    atomicAdd(&sHist[(w << 8) + ((k >> shift) & 255u)], 1u);
  }
  __syncthreads();

  // exclusive scan over 256 digit totals (threads 0..255 = 4 waves), then
  // per-(wave,digit) bases written back into sHist.
  uint32_t tot = 0;
  if (tid < 256) {
    #pragma unroll
    for (int w2 = 0; w2 < NWAVES; ++w2) tot += sHist[(w2 << 8) + tid];
  }
  uint32_t inc = tot;
  #pragma unroll
  for (int d = 1; d < 64; d <<= 1) {
    uint32_t o = __shfl_up(inc, (unsigned)d, 64);
    if (lane >= d) inc += o;
  }
  if (tid < 256 && lane == 63) sWsum[tid >> 6] = inc;
  __syncthreads();
  if (tid < 256) {
    uint32_t off = 0;
    for (int w2 = 0; w2 < (tid >> 6); ++w2) off += sWsum[w2];
    uint32_t run = off + (inc - tot);  // exclusive global base for this digit
    #pragma unroll
    for (int w2 = 0; w2 < NWAVES; ++w2) {
      uint32_t h = sHist[(w2 << 8) + tid];
      sHist[(w2 << 8) + tid] = run;
      run += h;
    }
  }
  __syncthreads();

  // stable scatter: ballot-match + mbcnt rank, leader bumps the base
  #pragma unroll
  for (int b = 0; b < 16; ++b) {
    uint32_t k = kreg[b];
    uint32_t d = (k >> shift) & 255u;
    unsigned long long m = ~0ull;
    #pragma unroll
    for (int bit = 0; bit < 8; ++bit) {
      unsigned long long bl = __ballot((d >> bit) & 1u);
      m &= ((d >> bit) & 1u) ? bl : ~bl;
    }
    uint32_t rank = __builtin_amdgcn_mbcnt_hi((uint32_t)(m >> 32),
                    __builtin_amdgcn_mbcnt_lo((uint32_t)m, 0u));
    uint32_t base = sHist[(w << 8) + d];
    dst[base + rank] = k;
    if (rank == 0) sHist[(w << 8) + d] = base + (uint32_t)__popcll(m);
  }
  __syncthreads();
}

__device__ __forceinline__ void sort16k(uint32_t* sA, uint32_t* sB, uint32_t* sHist,
                                        uint32_t* sWsum, int tid, int lane, int w) {
  radix_pass(sA, sB, sHist, sWsum, 0,  tid, lane, w);
  radix_pass(sB, sA, sHist, sWsum, 8,  tid, lane, w);
  radix_pass(sA, sB, sHist, sWsum, 16, tid, lane, w);
  radix_pass(sB, sA, sHist, sWsum, 24, tid, lane, w);
  // sorted result ends in sA
}

__global__ __launch_bounds__(NTHREADS)
void dmap_kernel(const float* __restrict__ x, const float* __restrict__ af,
                 const float* __restrict__ thr, float* __restrict__ out) {
  __shared__ __align__(16) uint32_t sA[NCOLS];   // 64 KB
  __shared__ __align__(16) uint32_t sB[NCOLS];   // 64 KB
  __shared__ uint32_t sHist[NWAVES * 256];       // 16 KB
  __shared__ uint32_t sWsum[4];
  __shared__ float sBucket[NWAVES * NTT];        // per-wave roc buckets
  __shared__ float sCol[NTT];
  __shared__ float sThr[NTHR];
  __shared__ float sRed[NWAVES][3];
  __shared__ float sMed[2];

  const int tid = (int)threadIdx.x;
  const int lane = tid & 63;
  const int w = tid >> 6;

  if (tid < NTHR) sThr[tid] = thr[tid];
  __syncthreads();

  for (int row = (int)blockIdx.x; row < MROWS; row += (int)gridDim.x) {
    for (int i = tid; i < NWAVES * NTT; i += NTHREADS) sBucket[i] = 0.0f;
    __syncthreads();

    float sumx = 0.0f, suma = 0.0f, wsum = 0.0f;

    // ---- load x row: row sum, roc buckets, keys into sA ----
    const float4* xr = reinterpret_cast<const float4*>(x) + (size_t)row * (NCOLS / 4);
    #pragma unroll
    for (int it = 0; it < 4; ++it) {
      float4 v = xr[it * NTHREADS + tid];
      float e[4] = {v.x, v.y, v.z, v.w};
      uint32_t ks[4];
      #pragma unroll
      for (int j = 0; j < 4; ++j) {
        float f = e[j];
        sumx += f;
        float ax = fabsf(f);
        int lo = 0, hi = NTHR;          // count of thresholds < ax, in [0,99]
        while (lo < hi) {
          int mid = (lo + hi) >> 1;
          if (sThr[mid] < ax) lo = mid + 1; else hi = mid;
        }
        atomicAdd(&sBucket[w * NTT + lo], f);
        ks[j] = f2k(f);
      }
      uint4 kk; kk.x = ks[0]; kk.y = ks[1]; kk.z = ks[2]; kk.w = ks[3];
      reinterpret_cast<uint4*>(sA)[it * NTHREADS + tid] = kk;
    }
    __syncthreads();

    // ---- roc: column sums over waves, suffix sum, write out ----
    if (tid < NTT) {
      float c = 0.0f;
      #pragma unroll
      for (int w2 = 0; w2 < NWAVES; ++w2) c += sBucket[w2 * NTT + tid];
      sCol[tid] = c;
    }
    __syncthreads();
    if (tid < NTT) {
      float sfx = 0.0f;
      for (int b = tid + 1; b < NTT; ++b) sfx += sCol[b];
      out[(size_t)row * NTT + tid] = (tid < NTHR) ? sfx * (1.0f / 16384.0f) : 0.0f;
    }

    // ---- sort x keys (ends in sA) ----
    sort16k(sA, sB, sHist, sWsum, tid, lane, w);

    // park this thread's 16 rank-paired sorted-x keys in registers
    uint4 ureg[4];
    #pragma unroll
    for (int it = 0; it < 4; ++it)
      ureg[it] = reinterpret_cast<const uint4*>(sA)[it * NTHREADS + tid];

    // ---- load anchor row (each thread overwrites only its own slots) ----
    const float4* ar = reinterpret_cast<const float4*>(af) + (size_t)row * (NCOLS / 4);
    #pragma unroll
    for (int it = 0; it < 4; ++it) {
      float4 v = ar[it * NTHREADS + tid];
      suma += v.x + v.y + v.z + v.w;
      uint4 kk;
      kk.x = f2k(v.x); kk.y = f2k(v.y); kk.z = f2k(v.z); kk.w = f2k(v.w);
      reinterpret_cast<uint4*>(sA)[it * NTHREADS + tid] = kk;
    }
    // visibility guaranteed by the clear+barrier at the start of radix_pass
    sort16k(sA, sB, sHist, sWsum, tid, lane, w);

    // ---- rank pairing: Wasserstein sum + medians ----
    #pragma unroll
    for (int it = 0; it < 4; ++it) {
      uint4 vk = reinterpret_cast<const uint4*>(sA)[it * NTHREADS + tid];
      uint4 uk = ureg[it];
      wsum += fabsf(k2f(uk.x) - k2f(vk.x));
      wsum += fabsf(k2f(uk.y) - k2f(vk.y));
      wsum += fabsf(k2f(uk.z) - k2f(vk.z));
      wsum += fabsf(k2f(uk.w) - k2f(vk.w));
      if (it == 1 && tid == NTHREADS - 1) {   // element index 8191 = (n-1)//2
        sMed[0] = k2f(uk.w);
        sMed[1] = k2f(vk.w);
      }
    }

    // ---- block reduce sums, write scalar outputs ----
    #pragma unroll
    for (int d = 32; d > 0; d >>= 1) {
      sumx += __shfl_xor(sumx, d, 64);
      suma += __shfl_xor(suma, d, 64);
      wsum += __shfl_xor(wsum, d, 64);
    }
    if (lane == 0) { sRed[w][0] = sumx; sRed[w][1] = suma; sRed[w][2] = wsum; }
    __syncthreads();
    if (tid == 0) {
      float SX = 0.0f, SA = 0.0f, SW = 0.0f;
      #pragma unroll
      for (int w2 = 0; w2 < NWAVES; ++w2) {
        SX += sRed[w2][0]; SA += sRed[w2][1]; SW += sRed[w2][2];
      }
      float md = sMed[0] - sMed[1];
      float sg = (md > 0.0f) ? 1.0f : (md < 0.0f ? -1.0f : 0.0f);
      out[153600 + row] = md;                                    // median_dist
      out[155136 + row] = SW * (1.0f / 16384.0f) * sg;           // wasser_dist
      out[156672 + row] = (SX - SA) * (1.0f / 16384.0f) * sg;    // mean_dist
    }
    __syncthreads();
  }
}

extern "C" void kernel_launch(void* const* d_in, const int* in_sizes, int n_in,
                              void* d_out, int out_size, void* d_ws, size_t ws_size,
                              hipStream_t stream) {
  (void)in_sizes; (void)n_in; (void)d_ws; (void)ws_size; (void)out_size;
  const float* x   = (const float*)d_in[0];
  const float* af  = (const float*)d_in[1];
  const float* thr = (const float*)d_in[2];
  float* out = (float*)d_out;
  hipLaunchKernelGGL(dmap_kernel, dim3(256), dim3(NTHREADS), 0, stream, x, af, thr, out);
}